// Round 5
// baseline (1453.610 us; speedup 1.0000x reference)
//
#include <hip/hip_runtime.h>
#include <hip/hip_bf16.h>

#define AC 32
#define H 8
#define C1 256
#define C2 128
#define NR 512
#define NA 256
#define MM 8
#define NN 768      // NR + NA
#define QKVD 1536   // AC * 6 * H
#define F 256       // AC * H planar feature dim

// Planar QKV layout: plane[role][row][c*8+h], role order = lq,lk,lv,rq,rk,rv
// (matches jnp.split chunk order within each 48-wide AC block).

// ---------------------------------------------------------------------------
// LayerNorm + QKV projection. Block = 256 threads, 8 rows per block.
// Writes PLANAR output: out[(role*nrows + row)*256 + (c*8+h)].
// ---------------------------------------------------------------------------
__global__ __launch_bounds__(256) void ln_qkv_kernel(
    const float* __restrict__ in, const float* __restrict__ g,
    const float* __restrict__ b, const float* __restrict__ W,
    float* __restrict__ out, int nrows)
{
    __shared__ float xn[8][C1];
    __shared__ float red[8];
    __shared__ float stats[2];
    const int t = threadIdx.x;
    const int base = blockIdx.x * 8;
    const int wid = t >> 6, lane = t & 63;
    const float gv = g[t], bv = b[t];

    for (int r = 0; r < 8; ++r) {
        const int row = base + r;
        float v = (row < nrows) ? in[(size_t)row * C1 + t] : 0.f;
        float s = v, s2 = v * v;
        #pragma unroll
        for (int off = 32; off; off >>= 1) {
            s  += __shfl_down(s, off);
            s2 += __shfl_down(s2, off);
        }
        if (lane == 0) { red[wid * 2] = s; red[wid * 2 + 1] = s2; }
        __syncthreads();
        if (t == 0) {
            float S  = red[0] + red[2] + red[4] + red[6];
            float S2 = red[1] + red[3] + red[5] + red[7];
            float mu = S / C1;
            float var = S2 / C1 - mu * mu;
            stats[0] = mu;
            stats[1] = rsqrtf(var + 1e-5f);
        }
        __syncthreads();
        xn[r][t] = (v - stats[0]) * stats[1] * gv + bv;
        __syncthreads();
    }

    for (int j = 0; j < 6; ++j) {
        const int col  = j * 256 + t;          // column in the 1536-wide QKV
        const int c    = col / 48;
        const int rem  = col - c * 48;
        const int role = rem >> 3;
        const int h    = rem & 7;
        const int f    = c * 8 + h;
        float acc[8] = {0.f, 0.f, 0.f, 0.f, 0.f, 0.f, 0.f, 0.f};
        for (int cc = 0; cc < C1; ++cc) {
            const float w = W[(size_t)cc * QKVD + col];
            #pragma unroll
            for (int r = 0; r < 8; ++r) acc[r] += xn[r][cc] * w;
        }
        float* op = out + ((size_t)role * nrows + base) * F + f;
        #pragma unroll
        for (int r = 0; r < 8; ++r) {
            if (base + r < nrows) op[(size_t)r * F] = acc[r];
        }
    }
}

// ---------------------------------------------------------------------------
// Pair-bias projection: bias[q][k][h] = factor * sum_c pair[q][k][c] * Wsel[c][h]
// One 32-lane group per (q,k); 8 (q,k) pairs per 256-thread block.
// ---------------------------------------------------------------------------
__global__ __launch_bounds__(256) void pair_bias_kernel(
    const float* __restrict__ pair, const float* __restrict__ Wrr,
    const float* __restrict__ Wll, const float* __restrict__ Wrl,
    const float* __restrict__ Wlr, float* __restrict__ bias)
{
    const int t = threadIdx.x;
    const int grp = t >> 5, l = t & 31;
    const int q = blockIdx.y;
    const int k = blockIdx.x * 8 + grp;

    const float* W;
    if (q < NR) W = (k < NR) ? Wrr : Wrl;
    else        W = (k < NR) ? Wlr : Wll;

    const float factor = 0.17677669529663687f;  // 1/sqrt(32)

    float wreg[4][8];
    #pragma unroll
    for (int i = 0; i < 4; ++i) {
        const float4 a  = *(const float4*)(W + (size_t)(l * 4 + i) * H);
        const float4 b4 = *(const float4*)(W + (size_t)(l * 4 + i) * H + 4);
        wreg[i][0] = a.x * factor;  wreg[i][1] = a.y * factor;
        wreg[i][2] = a.z * factor;  wreg[i][3] = a.w * factor;
        wreg[i][4] = b4.x * factor; wreg[i][5] = b4.y * factor;
        wreg[i][6] = b4.z * factor; wreg[i][7] = b4.w * factor;
    }

    const float4 p = *(const float4*)(pair + ((size_t)q * NN + k) * C2 + l * 4);
    float pr[4] = {p.x, p.y, p.z, p.w};

    float acc[8];
    #pragma unroll
    for (int h = 0; h < 8; ++h)
        acc[h] = pr[0] * wreg[0][h] + pr[1] * wreg[1][h] +
                 pr[2] * wreg[2][h] + pr[3] * wreg[3][h];

    #pragma unroll
    for (int off = 1; off < 32; off <<= 1) {
        #pragma unroll
        for (int h = 0; h < 8; ++h) acc[h] += __shfl_xor(acc[h], off);
    }

    if (l == 0) {
        float4* o = (float4*)(bias + ((size_t)q * NN + k) * H);
        o[0] = make_float4(acc[0], acc[1], acc[2], acc[3]);
        o[1] = make_float4(acc[4], acc[5], acc[6], acc[7]);
    }
}

// ---------------------------------------------------------------------------
// rr fold: bias[q][k][h] += rec_rq[q]·rec_rk[k] (per head), q,k < NR.
// The rr quadrant of the logit matrix is m-independent — compute it ONCE
// here instead of in all 8 m-replicas of the attention kernel.
// One block per q row; threads cover 2×256 keys.
// ---------------------------------------------------------------------------
__global__ __launch_bounds__(256) void rr_add_kernel(
    const float* __restrict__ rqkv, float* __restrict__ bias)
{
    __shared__ __align__(16) float qv[F];
    const int t = threadIdx.x;
    const int q = blockIdx.x;
    const size_t RSTR = (size_t)NR * F;
    qv[t] = rqkv[3 * RSTR + (size_t)q * F + t];   // rec_rq plane
    __syncthreads();
    const float4* q4 = (const float4*)qv;
    const float* recK = rqkv + 4 * RSTR;          // rec_rk plane

    #pragma unroll
    for (int rep = 0; rep < 2; ++rep) {
        const int k = rep * 256 + t;
        const float4* krow = (const float4*)(recK + (size_t)k * F);
        float acc[8] = {0.f, 0.f, 0.f, 0.f, 0.f, 0.f, 0.f, 0.f};
        #pragma unroll 8
        for (int j = 0; j < 64; ++j) {
            const float4 kv = krow[j];
            const float4 qq = q4[j];
            const int hb = (j & 1) * 4;
            acc[hb + 0] += qq.x * kv.x;
            acc[hb + 1] += qq.y * kv.y;
            acc[hb + 2] += qq.z * kv.z;
            acc[hb + 3] += qq.w * kv.w;
        }
        float* bp = bias + ((size_t)q * NN + k) * H;
        const float4 b1 = ((const float4*)bp)[0];
        const float4 b2 = ((const float4*)bp)[1];
        ((float4*)bp)[0] = make_float4(acc[0] + b1.x, acc[1] + b1.y,
                                       acc[2] + b1.z, acc[3] + b1.w);
        ((float4*)bp)[1] = make_float4(acc[4] + b2.x, acc[5] + b2.y,
                                       acc[6] + b2.z, acc[7] + b2.w);
    }
}

// ---------------------------------------------------------------------------
// Fused attention, TQ=2 q-rows per block. Planar QKV input. One block per
// (m, q-pair). Full 768-key logits (×2 rows) in LDS, block softmax, PV into
// rec_att (atomic, mean over m folded) / lig_att. K and V rows are fetched
// once per block and reused for both q rows.
// Top rows read the rr quadrant of `bias` as ready logits (rr_add folded).
// ---------------------------------------------------------------------------
__global__ __launch_bounds__(256) void attn_kernel(
    const float* __restrict__ rqkv, const float* __restrict__ lqkv,
    const float* __restrict__ bias, float* __restrict__ rec_att,
    float* __restrict__ lig_att)
{
    __shared__ __align__(16) float qA[2][F];   // q-vec vs rec keys
    __shared__ __align__(16) float qB[2][F];   // q-vec vs lig keys
    __shared__ float logit[2][NN][9];          // padded: bank-conflict-free
    __shared__ float red2[2][32][8];
    __shared__ float smax[2][8], sinv[2][8];

    const int t = threadIdx.x;
    const int q0 = blockIdx.x * 2, m = blockIdx.y;
    const bool top = q0 < NR;                  // NR even → pair never straddles

    // plane bases (row stride F). roles: lq0 lk1 lv2 rq3 rk4 rv5
    const size_t RSTR = (size_t)NR * F;
    const size_t LSTR = (size_t)MM * NA * F;
    const float* recP = rqkv;
    const float* ligP = lqkv + (size_t)m * NA * F;  // this m's row block

    #pragma unroll
    for (int r = 0; r < 2; ++r) {
        const float* qrow = top ? (recP + (size_t)(q0 + r) * F)
                                : (ligP + (size_t)(q0 + r - NR) * F);
        const size_t str = top ? RSTR : LSTR;
        qA[r][t] = qrow[3 * str + t];   // rq role
        qB[r][t] = qrow[0 * str + t];   // lq role
    }
    __syncthreads();

    // key planes: top rows use rk (plane 4), bottom rows lk (plane 1)
    const float* recK = recP + (top ? 4 : 1) * RSTR;
    const float* ligK = ligP + (top ? 4 : 1) * LSTR;

    // ---- logits ----
    if (top) {
        // k < NR: bias already holds rr_aff + rr_b (rr_add folded)
        #pragma unroll
        for (int rep = 0; rep < 2; ++rep) {
            const int k = rep * 256 + t;
            #pragma unroll
            for (int r = 0; r < 2; ++r) {
                const float* bp = bias + ((size_t)(q0 + r) * NN + k) * H;
                const float4 b1 = ((const float4*)bp)[0];
                const float4 b2 = ((const float4*)bp)[1];
                logit[r][k][0] = b1.x; logit[r][k][1] = b1.y;
                logit[r][k][2] = b1.z; logit[r][k][3] = b1.w;
                logit[r][k][4] = b2.x; logit[r][k][5] = b2.y;
                logit[r][k][6] = b2.z; logit[r][k][7] = b2.w;
            }
        }
        // k >= NR: rec_lq · lig_rk
        {
            const int k = NR + t;
            const float4* krow = (const float4*)(ligK + (size_t)t * F);
            float acc[2][8] = {{0.f}};
            #pragma unroll 8
            for (int j = 0; j < 64; ++j) {
                const float4 kv = krow[j];
                const int hb = (j & 1) * 4;
                #pragma unroll
                for (int r = 0; r < 2; ++r) {
                    const float4 qq = ((const float4*)qB[r])[j];
                    acc[r][hb + 0] += qq.x * kv.x;
                    acc[r][hb + 1] += qq.y * kv.y;
                    acc[r][hb + 2] += qq.z * kv.z;
                    acc[r][hb + 3] += qq.w * kv.w;
                }
            }
            #pragma unroll
            for (int r = 0; r < 2; ++r) {
                const float* bp = bias + ((size_t)(q0 + r) * NN + k) * H;
                const float4 b1 = ((const float4*)bp)[0];
                const float4 b2 = ((const float4*)bp)[1];
                logit[r][k][0] = acc[r][0] + b1.x; logit[r][k][1] = acc[r][1] + b1.y;
                logit[r][k][2] = acc[r][2] + b1.z; logit[r][k][3] = acc[r][3] + b1.w;
                logit[r][k][4] = acc[r][4] + b2.x; logit[r][k][5] = acc[r][5] + b2.y;
                logit[r][k][6] = acc[r][6] + b2.z; logit[r][k][7] = acc[r][7] + b2.w;
            }
        }
    } else {
        #pragma unroll
        for (int rep = 0; rep < 3; ++rep) {
            const int k = rep * 256 + t;
            const bool kr = k < NR;
            const float4* krow = (const float4*)(kr ? (recK + (size_t)k * F)
                                                    : (ligK + (size_t)(k - NR) * F));
            const float (*qsel)[F] = kr ? qA : qB;
            float acc[2][8] = {{0.f}};
            #pragma unroll 8
            for (int j = 0; j < 64; ++j) {
                const float4 kv = krow[j];
                const int hb = (j & 1) * 4;
                #pragma unroll
                for (int r = 0; r < 2; ++r) {
                    const float4 qq = ((const float4*)qsel[r])[j];
                    acc[r][hb + 0] += qq.x * kv.x;
                    acc[r][hb + 1] += qq.y * kv.y;
                    acc[r][hb + 2] += qq.z * kv.z;
                    acc[r][hb + 3] += qq.w * kv.w;
                }
            }
            #pragma unroll
            for (int r = 0; r < 2; ++r) {
                const float* bp = bias + ((size_t)(q0 + r) * NN + k) * H;
                const float4 b1 = ((const float4*)bp)[0];
                const float4 b2 = ((const float4*)bp)[1];
                logit[r][k][0] = acc[r][0] + b1.x; logit[r][k][1] = acc[r][1] + b1.y;
                logit[r][k][2] = acc[r][2] + b1.z; logit[r][k][3] = acc[r][3] + b1.w;
                logit[r][k][4] = acc[r][4] + b2.x; logit[r][k][5] = acc[r][5] + b2.y;
                logit[r][k][6] = acc[r][6] + b2.z; logit[r][k][7] = acc[r][7] + b2.w;
            }
        }
    }
    __syncthreads();

    // ---- softmax over k, per (row, head) ----
    const int h = t & 7, s = t >> 3;
    #pragma unroll
    for (int r = 0; r < 2; ++r) {
        float pmax = -1e30f;
        for (int j = 0; j < 24; ++j) pmax = fmaxf(pmax, logit[r][s * 24 + j][h]);
        red2[r][s][h] = pmax;
    }
    __syncthreads();
    if (t < 16) {
        const int r = t >> 3, hh = t & 7;
        float mx = red2[r][0][hh];
        for (int s2 = 1; s2 < 32; ++s2) mx = fmaxf(mx, red2[r][s2][hh]);
        smax[r][hh] = mx;
    }
    __syncthreads();
    #pragma unroll
    for (int r = 0; r < 2; ++r) {
        const float mxh = smax[r][h];
        float psum = 0.f;
        for (int j = 0; j < 24; ++j) {
            const int k = s * 24 + j;
            const float e = __expf(logit[r][k][h] - mxh);
            logit[r][k][h] = e;
            psum += e;
        }
        red2[r][s][h] = psum;
    }
    __syncthreads();
    if (t < 16) {
        const int r = t >> 3, hh = t & 7;
        float sm = 0.f;
        for (int s2 = 0; s2 < 32; ++s2) sm += red2[r][s2][hh];
        sinv[r][hh] = 1.0f / sm;
    }
    __syncthreads();

    // ---- PV ---- thread t owns feature f = t; V rows contiguous, shared by
    // both q rows (one global read, two FMAs).
    const float inv0 = sinv[0][h], inv1 = sinv[1][h];
    float aR0 = 0.f, aR1 = 0.f, aL0 = 0.f, aL1 = 0.f;
    if (top) {
        const float* Vlig = ligP + 5 * LSTR;              // lig_rv
        if (m == 0) {
            const float* Vrec = recP + 5 * RSTR;          // rec_rv
            #pragma unroll 4
            for (int k = 0; k < NR; ++k) {
                const float v = Vrec[(size_t)k * F + t];
                aR0 += logit[0][k][h] * v;
                aR1 += logit[1][k][h] * v;
            }
        }
        #pragma unroll 4
        for (int k = 0; k < NA; ++k) {
            const float v = Vlig[(size_t)k * F + t];
            aL0 += logit[0][NR + k][h] * v;
            aL1 += logit[1][NR + k][h] * v;
        }
        atomicAdd(&rec_att[(size_t)q0 * F + t],       inv0 * (aR0 + 0.125f * aL0));
        atomicAdd(&rec_att[(size_t)(q0 + 1) * F + t], inv1 * (aR1 + 0.125f * aL1));
    } else {
        const float* Vrec = recP + 2 * RSTR;              // rec_lv
        const float* Vlig = ligP + 2 * LSTR;              // lig_lv
        #pragma unroll 4
        for (int k = 0; k < NR; ++k) {
            const float v = Vrec[(size_t)k * F + t];
            aR0 += logit[0][k][h] * v;
            aR1 += logit[1][k][h] * v;
        }
        #pragma unroll 4
        for (int k = 0; k < NA; ++k) {
            const float v = Vlig[(size_t)k * F + t];
            aL0 += logit[0][NR + k][h] * v;
            aL1 += logit[1][NR + k][h] * v;
        }
        const int i0 = q0 - NR;
        lig_att[((size_t)m * NA + i0) * F + t]     = inv0 * (aR0 + aL0);
        lig_att[((size_t)m * NA + i0 + 1) * F + t] = inv1 * (aR1 + aL1);
    }
}

// ---------------------------------------------------------------------------
// Final projection: out[row][d] = att[row][:] @ W[:, d] + b[d]
// ---------------------------------------------------------------------------
__global__ __launch_bounds__(256) void final_kernel(
    const float* __restrict__ att, const float* __restrict__ W,
    const float* __restrict__ bfin, float* __restrict__ out, int nrows)
{
    __shared__ float x[8][C1];
    const int t = threadIdx.x;
    const int base = blockIdx.x * 8;
    #pragma unroll
    for (int r = 0; r < 8; ++r) {
        const int row = base + r;
        x[r][t] = (row < nrows) ? att[(size_t)row * C1 + t] : 0.f;
    }
    __syncthreads();
    float acc[8] = {0.f, 0.f, 0.f, 0.f, 0.f, 0.f, 0.f, 0.f};
    for (int cc = 0; cc < C1; ++cc) {
        const float w = W[(size_t)cc * C1 + t];
        #pragma unroll
        for (int r = 0; r < 8; ++r) acc[r] += x[r][cc] * w;
    }
    const float bb = bfin[t];
    #pragma unroll
    for (int r = 0; r < 8; ++r) {
        const int row = base + r;
        if (row < nrows) out[(size_t)row * C1 + t] = acc[r] + bb;
    }
}

// ---------------------------------------------------------------------------
extern "C" void kernel_launch(void* const* d_in, const int* in_sizes, int n_in,
                              void* d_out, int out_size, void* d_ws, size_t ws_size,
                              hipStream_t stream) {
    const float* rec_profile = (const float*)d_in[0];
    const float* lig_profile = (const float*)d_in[1];
    const float* pair        = (const float*)d_in[2];
    const float* rec_g       = (const float*)d_in[3];
    const float* rec_b       = (const float*)d_in[4];
    const float* lig_g       = (const float*)d_in[5];
    const float* lig_b       = (const float*)d_in[6];
    const float* W_rec_qkv   = (const float*)d_in[7];
    const float* W_lig_qkv   = (const float*)d_in[8];
    const float* W_rr        = (const float*)d_in[9];
    const float* W_ll        = (const float*)d_in[10];
    const float* W_rl        = (const float*)d_in[11];
    const float* W_lr        = (const float*)d_in[12];
    const float* W_rec_fin   = (const float*)d_in[13];
    const float* b_rec_fin   = (const float*)d_in[14];
    const float* W_lig_fin   = (const float*)d_in[15];
    const float* b_lig_fin   = (const float*)d_in[16];

    float* ws      = (float*)d_ws;
    float* rqkv    = ws;                                   // 6 planes * 512 * 256
    float* lqkv    = rqkv + (size_t)NR * QKVD;             // 6 planes * 2048 * 256
    float* bias    = lqkv + (size_t)MM * NA * QKVD;        // 768*768*8
    float* rec_att = bias + (size_t)NN * NN * H;           // 512*256
    float* lig_att = rec_att + (size_t)NR * F;             // 2048*256

    hipMemsetAsync(rec_att, 0, (size_t)NR * F * sizeof(float), stream);

    ln_qkv_kernel<<<NR / 8, 256, 0, stream>>>(rec_profile, rec_g, rec_b,
                                              W_rec_qkv, rqkv, NR);
    ln_qkv_kernel<<<MM * NA / 8, 256, 0, stream>>>(lig_profile, lig_g, lig_b,
                                                   W_lig_qkv, lqkv, MM * NA);
    pair_bias_kernel<<<dim3(NN / 8, NN), 256, 0, stream>>>(pair, W_rr, W_ll,
                                                           W_rl, W_lr, bias);
    rr_add_kernel<<<NR, 256, 0, stream>>>(rqkv, bias);
    attn_kernel<<<dim3(NN / 2, MM), 256, 0, stream>>>(rqkv, lqkv, bias,
                                                      rec_att, lig_att);

    float* rec_out = (float*)d_out;
    float* lig_out = rec_out + (size_t)NR * C1;
    final_kernel<<<NR / 8, 256, 0, stream>>>(rec_att, W_rec_fin, b_rec_fin,
                                             rec_out, NR);
    final_kernel<<<MM * NA / 8, 256, 0, stream>>>(lig_att, W_lig_fin, b_lig_fin,
                                                  lig_out, MM * NA);
}

// Round 8
// 1023.744 us; speedup vs baseline: 1.4199x; 1.4199x over previous
//
#include <hip/hip_runtime.h>
#include <hip/hip_bf16.h>

#define AC 32
#define H 8
#define C1 256
#define C2 128
#define NR 512
#define NA 256
#define MM 8
#define NN 768      // NR + NA
#define QKVD 1536   // AC * 6 * H
#define F 256       // AC * H planar feature dim

// Planar QKV layout: plane[role][row][c*8+h], role order = lq,lk,lv,rq,rk,rv
// (matches jnp.split chunk order within each 48-wide AC block).

// ---------------------------------------------------------------------------
// LayerNorm only: one 64-lane wave per row, 4 rows per block. No barriers.
// ---------------------------------------------------------------------------
__global__ __launch_bounds__(256) void ln_kernel(
    const float* __restrict__ in, const float* __restrict__ g,
    const float* __restrict__ b, float* __restrict__ xn, int nrows)
{
    const int t = threadIdx.x, w = t >> 6, lane = t & 63;
    const int row = blockIdx.x * 4 + w;
    if (row >= nrows) return;
    const float4 v = ((const float4*)(in + (size_t)row * C1))[lane];
    float s  = v.x + v.y + v.z + v.w;
    float s2 = v.x * v.x + v.y * v.y + v.z * v.z + v.w * v.w;
    #pragma unroll
    for (int off = 32; off; off >>= 1) {
        s  += __shfl_xor(s, off);
        s2 += __shfl_xor(s2, off);
    }
    const float mu = s * (1.0f / C1);
    const float rs = rsqrtf(s2 * (1.0f / C1) - mu * mu + 1e-5f);
    const float4 gv = ((const float4*)g)[lane];
    const float4 bv = ((const float4*)b)[lane];
    float4 o;
    o.x = (v.x - mu) * rs * gv.x + bv.x;
    o.y = (v.y - mu) * rs * gv.y + bv.y;
    o.z = (v.z - mu) * rs * gv.z + bv.z;
    o.w = (v.w - mu) * rs * gv.w + bv.w;
    ((float4*)(xn + (size_t)row * C1))[lane] = o;
}

// ---------------------------------------------------------------------------
// QKV projection GEMM, col-tiled: grid (nrows/4, 6). Block handles 4 rows ×
// 256 cols. Writes PLANAR output: out[(role*nrows + row)*256 + (c*8+h)].
// ---------------------------------------------------------------------------
__global__ __launch_bounds__(256) void qkv_gemm(
    const float* __restrict__ xn, const float* __restrict__ W,
    float* __restrict__ out, int nrows)
{
    __shared__ float x[4][C1];
    const int t = threadIdx.x;
    const int base = blockIdx.x * 4;
    #pragma unroll
    for (int r = 0; r < 4; ++r) x[r][t] = xn[(size_t)(base + r) * C1 + t];
    __syncthreads();

    const int col  = blockIdx.y * 256 + t;
    const int c    = col / 48;
    const int rem  = col - c * 48;
    const int role = rem >> 3;
    const int h    = rem & 7;
    const int f    = c * 8 + h;

    float a0 = 0.f, a1 = 0.f, a2 = 0.f, a3 = 0.f;
    #pragma unroll 4
    for (int cc = 0; cc < C1; ++cc) {
        const float w = W[(size_t)cc * QKVD + col];
        a0 += x[0][cc] * w;
        a1 += x[1][cc] * w;
        a2 += x[2][cc] * w;
        a3 += x[3][cc] * w;
    }
    float* op = out + ((size_t)role * nrows + base) * F + f;
    op[0 * F] = a0; op[1 * F] = a1; op[2 * F] = a2; op[3 * F] = a3;
}

// ---------------------------------------------------------------------------
// Pair-bias projection: bias[q][k][h] = factor * sum_c pair[q][k][c] * Wsel[c][h]
// ---------------------------------------------------------------------------
__global__ __launch_bounds__(256) void pair_bias_kernel(
    const float* __restrict__ pair, const float* __restrict__ Wrr,
    const float* __restrict__ Wll, const float* __restrict__ Wrl,
    const float* __restrict__ Wlr, float* __restrict__ bias)
{
    const int t = threadIdx.x;
    const int grp = t >> 5, l = t & 31;
    const int q = blockIdx.y;
    const int k = blockIdx.x * 8 + grp;

    const float* W;
    if (q < NR) W = (k < NR) ? Wrr : Wrl;
    else        W = (k < NR) ? Wlr : Wll;

    const float factor = 0.17677669529663687f;  // 1/sqrt(32)

    float wreg[4][8];
    #pragma unroll
    for (int i = 0; i < 4; ++i) {
        const float4 a  = *(const float4*)(W + (size_t)(l * 4 + i) * H);
        const float4 b4 = *(const float4*)(W + (size_t)(l * 4 + i) * H + 4);
        wreg[i][0] = a.x * factor;  wreg[i][1] = a.y * factor;
        wreg[i][2] = a.z * factor;  wreg[i][3] = a.w * factor;
        wreg[i][4] = b4.x * factor; wreg[i][5] = b4.y * factor;
        wreg[i][6] = b4.z * factor; wreg[i][7] = b4.w * factor;
    }

    const float4 p = *(const float4*)(pair + ((size_t)q * NN + k) * C2 + l * 4);
    float pr[4] = {p.x, p.y, p.z, p.w};

    float acc[8];
    #pragma unroll
    for (int h = 0; h < 8; ++h)
        acc[h] = pr[0] * wreg[0][h] + pr[1] * wreg[1][h] +
                 pr[2] * wreg[2][h] + pr[3] * wreg[3][h];

    #pragma unroll
    for (int off = 1; off < 32; off <<= 1) {
        #pragma unroll
        for (int h = 0; h < 8; ++h) acc[h] += __shfl_xor(acc[h], off);
    }

    if (l == 0) {
        float4* o = (float4*)(bias + ((size_t)q * NN + k) * H);
        o[0] = make_float4(acc[0], acc[1], acc[2], acc[3]);
        o[1] = make_float4(acc[4], acc[5], acc[6], acc[7]);
    }
}

// ---------------------------------------------------------------------------
// rr fold: bias[q][k][h] += rec_rq[q]·rec_rk[k] (per head), q,k < NR.
// m-independent — computed once instead of in all 8 m-replicas.
// ---------------------------------------------------------------------------
__global__ __launch_bounds__(256) void rr_add_kernel(
    const float* __restrict__ rqkv, float* __restrict__ bias)
{
    __shared__ __align__(16) float qv[F];
    const int t = threadIdx.x;
    const int q = blockIdx.x;
    const size_t RSTR = (size_t)NR * F;
    qv[t] = rqkv[3 * RSTR + (size_t)q * F + t];   // rec_rq plane
    __syncthreads();
    const float4* q4 = (const float4*)qv;
    const float* recK = rqkv + 4 * RSTR;          // rec_rk plane

    #pragma unroll
    for (int rep = 0; rep < 2; ++rep) {
        const int k = rep * 256 + t;
        const float4* krow = (const float4*)(recK + (size_t)k * F);
        float acc[8] = {0.f, 0.f, 0.f, 0.f, 0.f, 0.f, 0.f, 0.f};
        #pragma unroll 8
        for (int j = 0; j < 64; ++j) {
            const float4 kv = krow[j];
            const float4 qq = q4[j];
            const int hb = (j & 1) * 4;
            acc[hb + 0] += qq.x * kv.x;
            acc[hb + 1] += qq.y * kv.y;
            acc[hb + 2] += qq.z * kv.z;
            acc[hb + 3] += qq.w * kv.w;
        }
        float* bp = bias + ((size_t)q * NN + k) * H;
        const float4 b1 = ((const float4*)bp)[0];
        const float4 b2 = ((const float4*)bp)[1];
        ((float4*)bp)[0] = make_float4(acc[0] + b1.x, acc[1] + b1.y,
                                       acc[2] + b1.z, acc[3] + b1.w);
        ((float4*)bp)[1] = make_float4(acc[4] + b2.x, acc[5] + b2.y,
                                       acc[6] + b2.z, acc[7] + b2.w);
    }
}

// ---------------------------------------------------------------------------
// Flash-tiled fused attention, TQ=2 q-rows per block, 3 k-tiles of 256 with
// online softmax. LDS ~24 KB -> ~6 blocks/CU. One block per (m, q-pair).
// Top rows read the rr quadrant of `bias` as ready logits (rr_add folded).
// ---------------------------------------------------------------------------
__global__ __launch_bounds__(256) void attn_kernel(
    const float* __restrict__ rqkv, const float* __restrict__ lqkv,
    const float* __restrict__ bias, float* __restrict__ rec_att,
    float* __restrict__ lig_att)
{
    __shared__ __align__(16) float qA[2][F];   // rq role (vs rec keys)
    __shared__ __align__(16) float qB[2][F];   // lq role (vs lig keys)
    __shared__ float ptile[2][256][9];         // stride 9: conflict-free
    __shared__ float red2[2][32][8];
    __shared__ float Mrun[2][8], Drun[2][8], fct[2][8];

    const int t = threadIdx.x;
    const int q0 = blockIdx.x * 2, m = blockIdx.y;
    const bool top = q0 < NR;                  // NR even → pair same side

    const size_t RSTR = (size_t)NR * F;
    const size_t LSTR = (size_t)MM * NA * F;
    const float* recP = rqkv;
    const float* ligP = lqkv + (size_t)m * NA * F;

    #pragma unroll
    for (int r = 0; r < 2; ++r) {
        const float* qrow = top ? (recP + (size_t)(q0 + r) * F)
                                : (ligP + (size_t)(q0 + r - NR) * F);
        const size_t str = top ? RSTR : LSTR;
        qA[r][t] = qrow[3 * str + t];
        qB[r][t] = qrow[0 * str + t];
    }
    if (t < 16) { Mrun[t >> 3][t & 7] = -1e30f; Drun[t >> 3][t & 7] = 0.f; }
    __syncthreads();

    const float* recK = recP + (top ? 4 : 1) * RSTR;
    const float* ligK = ligP + (top ? 4 : 1) * LSTR;
    const float* Vrec = recP + (top ? 5 : 2) * RSTR;
    const float* Vlig = ligP + (top ? 5 : 2) * LSTR;

    const int h = t & 7, s = t >> 3;
    float accR0 = 0.f, accR1 = 0.f, accL0 = 0.f, accL1 = 0.f;

    for (int tl = 0; tl < 3; ++tl) {
        const int kbase = tl * 256;
        // ---- logits tile ----
        if (top && tl < 2) {
            #pragma unroll
            for (int r = 0; r < 2; ++r) {
                const float* bp = bias + ((size_t)(q0 + r) * NN + kbase + t) * H;
                const float4 b1 = ((const float4*)bp)[0];
                const float4 b2 = ((const float4*)bp)[1];
                ptile[r][t][0] = b1.x; ptile[r][t][1] = b1.y;
                ptile[r][t][2] = b1.z; ptile[r][t][3] = b1.w;
                ptile[r][t][4] = b2.x; ptile[r][t][5] = b2.y;
                ptile[r][t][6] = b2.z; ptile[r][t][7] = b2.w;
            }
        } else {
            const float4* krow = (const float4*)((tl < 2)
                ? (recK + (size_t)(kbase + t) * F)
                : (ligK + (size_t)t * F));
            float acc[2][8] = {{0.f}};
            #pragma unroll 8
            for (int j = 0; j < 64; ++j) {
                const float4 kv = krow[j];
                const int hb = (j & 1) * 4;
                #pragma unroll
                for (int r = 0; r < 2; ++r) {
                    const float4 qq = (tl < 2) ? ((const float4*)qA[r])[j]
                                               : ((const float4*)qB[r])[j];
                    acc[r][hb + 0] += qq.x * kv.x;
                    acc[r][hb + 1] += qq.y * kv.y;
                    acc[r][hb + 2] += qq.z * kv.z;
                    acc[r][hb + 3] += qq.w * kv.w;
                }
            }
            #pragma unroll
            for (int r = 0; r < 2; ++r) {
                const float* bp = bias + ((size_t)(q0 + r) * NN + kbase + t) * H;
                const float4 b1 = ((const float4*)bp)[0];
                const float4 b2 = ((const float4*)bp)[1];
                ptile[r][t][0] = acc[r][0] + b1.x; ptile[r][t][1] = acc[r][1] + b1.y;
                ptile[r][t][2] = acc[r][2] + b1.z; ptile[r][t][3] = acc[r][3] + b1.w;
                ptile[r][t][4] = acc[r][4] + b2.x; ptile[r][t][5] = acc[r][5] + b2.y;
                ptile[r][t][6] = acc[r][6] + b2.z; ptile[r][t][7] = acc[r][7] + b2.w;
            }
        }
        __syncthreads();

        // ---- tile max per (r,h) ----
        #pragma unroll
        for (int r = 0; r < 2; ++r) {
            float pm = ptile[r][s * 8][h];
            #pragma unroll
            for (int j = 1; j < 8; ++j) pm = fmaxf(pm, ptile[r][s * 8 + j][h]);
            red2[r][s][h] = pm;
        }
        __syncthreads();
        if (t < 16) {
            const int r = t >> 3, hh = t & 7;
            float mx = red2[r][0][hh];
            for (int s2 = 1; s2 < 32; ++s2) mx = fmaxf(mx, red2[r][s2][hh]);
            const float Mo = Mrun[r][hh];
            const float Mn = fmaxf(Mo, mx);
            fct[r][hh]  = __expf(Mo - Mn);
            Mrun[r][hh] = Mn;
        }
        __syncthreads();

        // ---- exp + partial sums; rescale accumulators ----
        #pragma unroll
        for (int r = 0; r < 2; ++r) {
            const float Mn = Mrun[r][h];
            float ps = 0.f;
            #pragma unroll
            for (int j = 0; j < 8; ++j) {
                const int kk = s * 8 + j;
                const float e = __expf(ptile[r][kk][h] - Mn);
                ptile[r][kk][h] = e;
                ps += e;
            }
            red2[r][s][h] = ps;
        }
        {
            const float f0 = fct[0][h], f1 = fct[1][h];
            accR0 *= f0; accL0 *= f0;
            accR1 *= f1; accL1 *= f1;
        }
        __syncthreads();
        if (t < 16) {
            const int r = t >> 3, hh = t & 7;
            float ts = 0.f;
            for (int s2 = 0; s2 < 32; ++s2) ts += red2[r][s2][hh];
            Drun[r][hh] = Drun[r][hh] * fct[r][hh] + ts;
        }

        // ---- PV over this tile ----
        const bool doPV = (tl == 2) || (!top) || (m == 0);
        if (doPV) {
            if (tl < 2) {
                const float* Vp = Vrec + (size_t)kbase * F;
                #pragma unroll 8
                for (int kk = 0; kk < 256; ++kk) {
                    const float v = Vp[(size_t)kk * F + t];
                    accR0 += ptile[0][kk][h] * v;
                    accR1 += ptile[1][kk][h] * v;
                }
            } else {
                #pragma unroll 8
                for (int kk = 0; kk < 256; ++kk) {
                    const float v = Vlig[(size_t)kk * F + t];
                    accL0 += ptile[0][kk][h] * v;
                    accL1 += ptile[1][kk][h] * v;
                }
            }
        }
        __syncthreads();
    }

    const float i0 = 1.0f / Drun[0][h];
    const float i1 = 1.0f / Drun[1][h];
    if (top) {
        atomicAdd(&rec_att[(size_t)q0 * F + t],       i0 * (accR0 + 0.125f * accL0));
        atomicAdd(&rec_att[(size_t)(q0 + 1) * F + t], i1 * (accR1 + 0.125f * accL1));
    } else {
        const int i = q0 - NR;
        lig_att[((size_t)m * NA + i) * F + t]     = i0 * (accR0 + accL0);
        lig_att[((size_t)m * NA + i + 1) * F + t] = i1 * (accR1 + accL1);
    }
}

// ---------------------------------------------------------------------------
// Final projection: out[row][d] = att[row][:] @ W[:, d] + b[d]. 4 rows/block.
// ---------------------------------------------------------------------------
__global__ __launch_bounds__(256) void final_gemm(
    const float* __restrict__ att, const float* __restrict__ W,
    const float* __restrict__ bfin, float* __restrict__ out, int nrows)
{
    __shared__ float x[4][C1];
    const int t = threadIdx.x;
    const int base = blockIdx.x * 4;
    #pragma unroll
    for (int r = 0; r < 4; ++r) x[r][t] = att[(size_t)(base + r) * C1 + t];
    __syncthreads();
    float a0 = 0.f, a1 = 0.f, a2 = 0.f, a3 = 0.f;
    #pragma unroll 4
    for (int cc = 0; cc < C1; ++cc) {
        const float w = W[(size_t)cc * C1 + t];
        a0 += x[0][cc] * w;
        a1 += x[1][cc] * w;
        a2 += x[2][cc] * w;
        a3 += x[3][cc] * w;
    }
    const float bb = bfin[t];
    out[(size_t)(base + 0) * C1 + t] = a0 + bb;
    out[(size_t)(base + 1) * C1 + t] = a1 + bb;
    out[(size_t)(base + 2) * C1 + t] = a2 + bb;
    out[(size_t)(base + 3) * C1 + t] = a3 + bb;
}

// ---------------------------------------------------------------------------
extern "C" void kernel_launch(void* const* d_in, const int* in_sizes, int n_in,
                              void* d_out, int out_size, void* d_ws, size_t ws_size,
                              hipStream_t stream) {
    const float* rec_profile = (const float*)d_in[0];
    const float* lig_profile = (const float*)d_in[1];
    const float* pair        = (const float*)d_in[2];
    const float* rec_g       = (const float*)d_in[3];
    const float* rec_b       = (const float*)d_in[4];
    const float* lig_g       = (const float*)d_in[5];
    const float* lig_b       = (const float*)d_in[6];
    const float* W_rec_qkv   = (const float*)d_in[7];
    const float* W_lig_qkv   = (const float*)d_in[8];
    const float* W_rr        = (const float*)d_in[9];
    const float* W_ll        = (const float*)d_in[10];
    const float* W_rl        = (const float*)d_in[11];
    const float* W_lr        = (const float*)d_in[12];
    const float* W_rec_fin   = (const float*)d_in[13];
    const float* b_rec_fin   = (const float*)d_in[14];
    const float* W_lig_fin   = (const float*)d_in[15];
    const float* b_lig_fin   = (const float*)d_in[16];

    float* ws      = (float*)d_ws;
    float* rqkv    = ws;                                   // 6 planes * 512 * 256
    float* lqkv    = rqkv + (size_t)NR * QKVD;             // 6 planes * 2048 * 256
    float* bias    = lqkv + (size_t)MM * NA * QKVD;        // 768*768*8
    float* rec_att = bias + (size_t)NN * NN * H;           // 512*256
    float* lig_att = rec_att + (size_t)NR * F;             // 2048*256

    // xn buffers ALIAS the att buffers (dead before attn runs; exact fit).
    float* xn_rec = rec_att;
    float* xn_lig = lig_att;

    ln_kernel<<<NR / 4, 256, 0, stream>>>(rec_profile, rec_g, rec_b, xn_rec, NR);
    ln_kernel<<<MM * NA / 4, 256, 0, stream>>>(lig_profile, lig_g, lig_b,
                                               xn_lig, MM * NA);
    qkv_gemm<<<dim3(NR / 4, 6), 256, 0, stream>>>(xn_rec, W_rec_qkv, rqkv, NR);
    qkv_gemm<<<dim3(MM * NA / 4, 6), 256, 0, stream>>>(xn_lig, W_lig_qkv,
                                                       lqkv, MM * NA);
    pair_bias_kernel<<<dim3(NN / 8, NN), 256, 0, stream>>>(pair, W_rr, W_ll,
                                                           W_rl, W_lr, bias);
    rr_add_kernel<<<NR, 256, 0, stream>>>(rqkv, bias);

    // rec_att must be zeroed AFTER qkv_gemm consumed xn_rec (same memory).
    hipMemsetAsync(rec_att, 0, (size_t)NR * F * sizeof(float), stream);

    attn_kernel<<<dim3(NN / 2, MM), 256, 0, stream>>>(rqkv, lqkv, bias,
                                                      rec_att, lig_att);

    float* rec_out = (float*)d_out;
    float* lig_out = rec_out + (size_t)NR * C1;
    final_gemm<<<NR / 4, 256, 0, stream>>>(rec_att, W_rec_fin, b_rec_fin,
                                           rec_out, NR);
    final_gemm<<<MM * NA / 4, 256, 0, stream>>>(lig_att, W_lig_fin, b_lig_fin,
                                                lig_out, MM * NA);
}

// Round 11
// 869.775 us; speedup vs baseline: 1.6712x; 1.1770x over previous
//
#include <hip/hip_runtime.h>
#include <hip/hip_bf16.h>

#define AC 32
#define H 8
#define C1 256
#define C2 128
#define NR 512
#define NA 256
#define MM 8
#define NN 768      // NR + NA
#define QKVD 1536   // AC * 6 * H
#define F 256       // AC * H planar feature dim

// Planar QKV layout: plane[role][row][c*8+h], role order = lq,lk,lv,rq,rk,rv
// (matches jnp.split chunk order within each 48-wide AC block).

// ---------------------------------------------------------------------------
// LayerNorm only: one 64-lane wave per row, 4 rows per block. No barriers.
// ---------------------------------------------------------------------------
__global__ __launch_bounds__(256) void ln_kernel(
    const float* __restrict__ in, const float* __restrict__ g,
    const float* __restrict__ b, float* __restrict__ xn, int nrows)
{
    const int t = threadIdx.x, w = t >> 6, lane = t & 63;
    const int row = blockIdx.x * 4 + w;
    if (row >= nrows) return;
    const float4 v = ((const float4*)(in + (size_t)row * C1))[lane];
    float s  = v.x + v.y + v.z + v.w;
    float s2 = v.x * v.x + v.y * v.y + v.z * v.z + v.w * v.w;
    #pragma unroll
    for (int off = 32; off; off >>= 1) {
        s  += __shfl_xor(s, off);
        s2 += __shfl_xor(s2, off);
    }
    const float mu = s * (1.0f / C1);
    const float rs = rsqrtf(s2 * (1.0f / C1) - mu * mu + 1e-5f);
    const float4 gv = ((const float4*)g)[lane];
    const float4 bv = ((const float4*)b)[lane];
    float4 o;
    o.x = (v.x - mu) * rs * gv.x + bv.x;
    o.y = (v.y - mu) * rs * gv.y + bv.y;
    o.z = (v.z - mu) * rs * gv.z + bv.z;
    o.w = (v.w - mu) * rs * gv.w + bv.w;
    ((float4*)(xn + (size_t)row * C1))[lane] = o;
}

// ---------------------------------------------------------------------------
// QKV projection GEMM, col-tiled: grid (nrows/4, 6). Block handles 4 rows ×
// 256 cols. Writes PLANAR output: out[(role*nrows + row)*256 + (c*8+h)].
// ---------------------------------------------------------------------------
__global__ __launch_bounds__(256) void qkv_gemm(
    const float* __restrict__ xn, const float* __restrict__ W,
    float* __restrict__ out, int nrows)
{
    __shared__ float x[4][C1];
    const int t = threadIdx.x;
    const int base = blockIdx.x * 4;
    #pragma unroll
    for (int r = 0; r < 4; ++r) x[r][t] = xn[(size_t)(base + r) * C1 + t];
    __syncthreads();

    const int col  = blockIdx.y * 256 + t;
    const int c    = col / 48;
    const int rem  = col - c * 48;
    const int role = rem >> 3;
    const int h    = rem & 7;
    const int f    = c * 8 + h;

    float a0 = 0.f, a1 = 0.f, a2 = 0.f, a3 = 0.f;
    #pragma unroll 4
    for (int cc = 0; cc < C1; ++cc) {
        const float w = W[(size_t)cc * QKVD + col];
        a0 += x[0][cc] * w;
        a1 += x[1][cc] * w;
        a2 += x[2][cc] * w;
        a3 += x[3][cc] * w;
    }
    float* op = out + ((size_t)role * nrows + base) * F + f;
    op[0 * F] = a0; op[1 * F] = a1; op[2 * F] = a2; op[3 * F] = a3;
}

// ---------------------------------------------------------------------------
// Pair-bias projection: bias[q][k][h] = factor * sum_c pair[q][k][c] * Wsel[c][h]
// One 32-lane group per (q,k); 8 groups/block; block loops 4 k-chunks
// (one q × 32 k's per block, W regs reused).
// Reduction = reduce-scatter butterfly: 9 shuffles/pair instead of 40.
// ---------------------------------------------------------------------------
__global__ __launch_bounds__(256) void pair_bias_kernel(
    const float* __restrict__ pair, const float* __restrict__ Wrr,
    const float* __restrict__ Wll, const float* __restrict__ Wrl,
    const float* __restrict__ Wlr, float* __restrict__ bias)
{
    const int t = threadIdx.x;
    const int grp = t >> 5, l = t & 31;
    const int q = blockIdx.y;
    const int kbase = blockIdx.x * 32;   // 32-chunks never straddle NR=512

    const float* W;
    if (q < NR) W = (kbase < NR) ? Wrr : Wrl;
    else        W = (kbase < NR) ? Wlr : Wll;

    const float factor = 0.17677669529663687f;  // 1/sqrt(32)

    float wreg[4][8];
    #pragma unroll
    for (int i = 0; i < 4; ++i) {
        const float4 a  = *(const float4*)(W + (size_t)(l * 4 + i) * H);
        const float4 b4 = *(const float4*)(W + (size_t)(l * 4 + i) * H + 4);
        wreg[i][0] = a.x * factor;  wreg[i][1] = a.y * factor;
        wreg[i][2] = a.z * factor;  wreg[i][3] = a.w * factor;
        wreg[i][4] = b4.x * factor; wreg[i][5] = b4.y * factor;
        wreg[i][6] = b4.z * factor; wreg[i][7] = b4.w * factor;
    }

    // lane's output h after reduce-scatter (bit-reversed 3-bit lane id)
    const int hsel = 4 * (l & 1) + 2 * ((l >> 1) & 1) + ((l >> 2) & 1);

    #pragma unroll
    for (int kk = 0; kk < 4; ++kk) {
        const int k = kbase + kk * 8 + grp;

        const float4 p = *(const float4*)(pair + ((size_t)q * NN + k) * C2 + l * 4);
        float pr[4] = {p.x, p.y, p.z, p.w};

        float acc[8];
        #pragma unroll
        for (int h = 0; h < 8; ++h)
            acc[h] = pr[0] * wreg[0][h] + pr[1] * wreg[1][h] +
                     pr[2] * wreg[2][h] + pr[3] * wreg[3][h];

        // ---- reduce-scatter over lane bits 0..2 (static indices only) ----
        // round 1 (xor 1): keep 4 of 8
        {
            const bool b = (l & 1) != 0;       // b=0 keep h0-3, b=1 keep h4-7
            float s0 = b ? acc[0] : acc[4];
            float s1 = b ? acc[1] : acc[5];
            float s2 = b ? acc[2] : acc[6];
            float s3 = b ? acc[3] : acc[7];
            const float r0 = __shfl_xor(s0, 1);
            const float r1 = __shfl_xor(s1, 1);
            const float r2 = __shfl_xor(s2, 1);
            const float r3 = __shfl_xor(s3, 1);
            acc[0] = (b ? acc[4] : acc[0]) + r0;
            acc[1] = (b ? acc[5] : acc[1]) + r1;
            acc[2] = (b ? acc[6] : acc[2]) + r2;
            acc[3] = (b ? acc[7] : acc[3]) + r3;
        }
        // round 2 (xor 2): keep 2 of 4
        {
            const bool b = (l & 2) != 0;
            float s0 = b ? acc[0] : acc[2];
            float s1 = b ? acc[1] : acc[3];
            const float r0 = __shfl_xor(s0, 2);
            const float r1 = __shfl_xor(s1, 2);
            acc[0] = (b ? acc[2] : acc[0]) + r0;
            acc[1] = (b ? acc[3] : acc[1]) + r1;
        }
        // round 3 (xor 4): keep 1 of 2
        float v;
        {
            const bool b = (l & 4) != 0;
            float s0 = b ? acc[0] : acc[1];
            const float r0 = __shfl_xor(s0, 4);
            v = (b ? acc[1] : acc[0]) + r0;
        }
        // full-sum butterflies across remaining lane bits (same h at l^8, l^16)
        v += __shfl_xor(v, 8);
        v += __shfl_xor(v, 16);

        if (l < 8)
            bias[((size_t)q * NN + k) * H + hsel] = v;
    }
}

// ---------------------------------------------------------------------------
// rr fold: bias[q][k][h] += rec_rq[q]·rec_rk[k] (per head), q,k < NR.
// m-independent — computed once instead of in all 8 m-replicas.
// ---------------------------------------------------------------------------
__global__ __launch_bounds__(256) void rr_add_kernel(
    const float* __restrict__ rqkv, float* __restrict__ bias)
{
    __shared__ __align__(16) float qv[F];
    const int t = threadIdx.x;
    const int q = blockIdx.x;
    const size_t RSTR = (size_t)NR * F;
    qv[t] = rqkv[3 * RSTR + (size_t)q * F + t];   // rec_rq plane
    __syncthreads();
    const float4* q4 = (const float4*)qv;
    const float* recK = rqkv + 4 * RSTR;          // rec_rk plane

    #pragma unroll
    for (int rep = 0; rep < 2; ++rep) {
        const int k = rep * 256 + t;
        const float4* krow = (const float4*)(recK + (size_t)k * F);
        float acc[8] = {0.f, 0.f, 0.f, 0.f, 0.f, 0.f, 0.f, 0.f};
        #pragma unroll 8
        for (int j = 0; j < 64; ++j) {
            const float4 kv = krow[j];
            const float4 qq = q4[j];
            const int hb = (j & 1) * 4;
            acc[hb + 0] += qq.x * kv.x;
            acc[hb + 1] += qq.y * kv.y;
            acc[hb + 2] += qq.z * kv.z;
            acc[hb + 3] += qq.w * kv.w;
        }
        float* bp = bias + ((size_t)q * NN + k) * H;
        const float4 b1 = ((const float4*)bp)[0];
        const float4 b2 = ((const float4*)bp)[1];
        ((float4*)bp)[0] = make_float4(acc[0] + b1.x, acc[1] + b1.y,
                                       acc[2] + b1.z, acc[3] + b1.w);
        ((float4*)bp)[1] = make_float4(acc[4] + b2.x, acc[5] + b2.y,
                                       acc[6] + b2.z, acc[7] + b2.w);
    }
}

// ---------------------------------------------------------------------------
// Flash-tiled fused attention, TQ=2 q-rows per block, 3 k-tiles of 256 with
// online softmax. LDS ~24 KB -> ~6 blocks/CU. One block per (m, q-pair).
// Top rows read the rr quadrant of `bias` as ready logits (rr_add folded).
// ---------------------------------------------------------------------------
__global__ __launch_bounds__(256) void attn_kernel(
    const float* __restrict__ rqkv, const float* __restrict__ lqkv,
    const float* __restrict__ bias, float* __restrict__ rec_att,
    float* __restrict__ lig_att)
{
    __shared__ __align__(16) float qA[2][F];   // rq role (vs rec keys)
    __shared__ __align__(16) float qB[2][F];   // lq role (vs lig keys)
    __shared__ float ptile[2][256][9];         // stride 9: conflict-free
    __shared__ float red2[2][32][8];
    __shared__ float Mrun[2][8], Drun[2][8], fct[2][8];

    const int t = threadIdx.x;
    const int q0 = blockIdx.x * 2, m = blockIdx.y;
    const bool top = q0 < NR;                  // NR even → pair same side

    const size_t RSTR = (size_t)NR * F;
    const size_t LSTR = (size_t)MM * NA * F;
    const float* recP = rqkv;
    const float* ligP = lqkv + (size_t)m * NA * F;

    #pragma unroll
    for (int r = 0; r < 2; ++r) {
        const float* qrow = top ? (recP + (size_t)(q0 + r) * F)
                                : (ligP + (size_t)(q0 + r - NR) * F);
        const size_t str = top ? RSTR : LSTR;
        qA[r][t] = qrow[3 * str + t];
        qB[r][t] = qrow[0 * str + t];
    }
    if (t < 16) { Mrun[t >> 3][t & 7] = -1e30f; Drun[t >> 3][t & 7] = 0.f; }
    __syncthreads();

    const float* recK = recP + (top ? 4 : 1) * RSTR;
    const float* ligK = ligP + (top ? 4 : 1) * LSTR;
    const float* Vrec = recP + (top ? 5 : 2) * RSTR;
    const float* Vlig = ligP + (top ? 5 : 2) * LSTR;

    const int h = t & 7, s = t >> 3;
    float accR0 = 0.f, accR1 = 0.f, accL0 = 0.f, accL1 = 0.f;

    for (int tl = 0; tl < 3; ++tl) {
        const int kbase = tl * 256;
        // ---- logits tile ----
        if (top && tl < 2) {
            #pragma unroll
            for (int r = 0; r < 2; ++r) {
                const float* bp = bias + ((size_t)(q0 + r) * NN + kbase + t) * H;
                const float4 b1 = ((const float4*)bp)[0];
                const float4 b2 = ((const float4*)bp)[1];
                ptile[r][t][0] = b1.x; ptile[r][t][1] = b1.y;
                ptile[r][t][2] = b1.z; ptile[r][t][3] = b1.w;
                ptile[r][t][4] = b2.x; ptile[r][t][5] = b2.y;
                ptile[r][t][6] = b2.z; ptile[r][t][7] = b2.w;
            }
        } else {
            const float4* krow = (const float4*)((tl < 2)
                ? (recK + (size_t)(kbase + t) * F)
                : (ligK + (size_t)t * F));
            float acc[2][8] = {{0.f}};
            #pragma unroll 8
            for (int j = 0; j < 64; ++j) {
                const float4 kv = krow[j];
                const int hb = (j & 1) * 4;
                #pragma unroll
                for (int r = 0; r < 2; ++r) {
                    const float4 qq = (tl < 2) ? ((const float4*)qA[r])[j]
                                               : ((const float4*)qB[r])[j];
                    acc[r][hb + 0] += qq.x * kv.x;
                    acc[r][hb + 1] += qq.y * kv.y;
                    acc[r][hb + 2] += qq.z * kv.z;
                    acc[r][hb + 3] += qq.w * kv.w;
                }
            }
            #pragma unroll
            for (int r = 0; r < 2; ++r) {
                const float* bp = bias + ((size_t)(q0 + r) * NN + kbase + t) * H;
                const float4 b1 = ((const float4*)bp)[0];
                const float4 b2 = ((const float4*)bp)[1];
                ptile[r][t][0] = acc[r][0] + b1.x; ptile[r][t][1] = acc[r][1] + b1.y;
                ptile[r][t][2] = acc[r][2] + b1.z; ptile[r][t][3] = acc[r][3] + b1.w;
                ptile[r][t][4] = acc[r][4] + b2.x; ptile[r][t][5] = acc[r][5] + b2.y;
                ptile[r][t][6] = acc[r][6] + b2.z; ptile[r][t][7] = acc[r][7] + b2.w;
            }
        }
        __syncthreads();

        // ---- tile max per (r,h) ----
        #pragma unroll
        for (int r = 0; r < 2; ++r) {
            float pm = ptile[r][s * 8][h];
            #pragma unroll
            for (int j = 1; j < 8; ++j) pm = fmaxf(pm, ptile[r][s * 8 + j][h]);
            red2[r][s][h] = pm;
        }
        __syncthreads();
        if (t < 16) {
            const int r = t >> 3, hh = t & 7;
            float mx = red2[r][0][hh];
            for (int s2 = 1; s2 < 32; ++s2) mx = fmaxf(mx, red2[r][s2][hh]);
            const float Mo = Mrun[r][hh];
            const float Mn = fmaxf(Mo, mx);
            fct[r][hh]  = __expf(Mo - Mn);
            Mrun[r][hh] = Mn;
        }
        __syncthreads();

        // ---- exp + partial sums; rescale accumulators ----
        #pragma unroll
        for (int r = 0; r < 2; ++r) {
            const float Mn = Mrun[r][h];
            float ps = 0.f;
            #pragma unroll
            for (int j = 0; j < 8; ++j) {
                const int kk = s * 8 + j;
                const float e = __expf(ptile[r][kk][h] - Mn);
                ptile[r][kk][h] = e;
                ps += e;
            }
            red2[r][s][h] = ps;
        }
        {
            const float f0 = fct[0][h], f1 = fct[1][h];
            accR0 *= f0; accL0 *= f0;
            accR1 *= f1; accL1 *= f1;
        }
        __syncthreads();
        if (t < 16) {
            const int r = t >> 3, hh = t & 7;
            float ts = 0.f;
            for (int s2 = 0; s2 < 32; ++s2) ts += red2[r][s2][hh];
            Drun[r][hh] = Drun[r][hh] * fct[r][hh] + ts;
        }

        // ---- PV over this tile ----
        const bool doPV = (tl == 2) || (!top) || (m == 0);
        if (doPV) {
            if (tl < 2) {
                const float* Vp = Vrec + (size_t)kbase * F;
                #pragma unroll 8
                for (int kk = 0; kk < 256; ++kk) {
                    const float v = Vp[(size_t)kk * F + t];
                    accR0 += ptile[0][kk][h] * v;
                    accR1 += ptile[1][kk][h] * v;
                }
            } else {
                #pragma unroll 8
                for (int kk = 0; kk < 256; ++kk) {
                    const float v = Vlig[(size_t)kk * F + t];
                    accL0 += ptile[0][kk][h] * v;
                    accL1 += ptile[1][kk][h] * v;
                }
            }
        }
        __syncthreads();
    }

    const float i0 = 1.0f / Drun[0][h];
    const float i1 = 1.0f / Drun[1][h];
    if (top) {
        atomicAdd(&rec_att[(size_t)q0 * F + t],       i0 * (accR0 + 0.125f * accL0));
        atomicAdd(&rec_att[(size_t)(q0 + 1) * F + t], i1 * (accR1 + 0.125f * accL1));
    } else {
        const int i = q0 - NR;
        lig_att[((size_t)m * NA + i) * F + t]     = i0 * (accR0 + accL0);
        lig_att[((size_t)m * NA + i + 1) * F + t] = i1 * (accR1 + accL1);
    }
}

// ---------------------------------------------------------------------------
// Final projection: out[row][d] = att[row][:] @ W[:, d] + b[d]. 4 rows/block.
// ---------------------------------------------------------------------------
__global__ __launch_bounds__(256) void final_gemm(
    const float* __restrict__ att, const float* __restrict__ W,
    const float* __restrict__ bfin, float* __restrict__ out, int nrows)
{
    __shared__ float x[4][C1];
    const int t = threadIdx.x;
    const int base = blockIdx.x * 4;
    #pragma unroll
    for (int r = 0; r < 4; ++r) x[r][t] = att[(size_t)(base + r) * C1 + t];
    __syncthreads();
    float a0 = 0.f, a1 = 0.f, a2 = 0.f, a3 = 0.f;
    #pragma unroll 4
    for (int cc = 0; cc < C1; ++cc) {
        const float w = W[(size_t)cc * C1 + t];
        a0 += x[0][cc] * w;
        a1 += x[1][cc] * w;
        a2 += x[2][cc] * w;
        a3 += x[3][cc] * w;
    }
    const float bb = bfin[t];
    out[(size_t)(base + 0) * C1 + t] = a0 + bb;
    out[(size_t)(base + 1) * C1 + t] = a1 + bb;
    out[(size_t)(base + 2) * C1 + t] = a2 + bb;
    out[(size_t)(base + 3) * C1 + t] = a3 + bb;
}

// ---------------------------------------------------------------------------
extern "C" void kernel_launch(void* const* d_in, const int* in_sizes, int n_in,
                              void* d_out, int out_size, void* d_ws, size_t ws_size,
                              hipStream_t stream) {
    const float* rec_profile = (const float*)d_in[0];
    const float* lig_profile = (const float*)d_in[1];
    const float* pair        = (const float*)d_in[2];
    const float* rec_g       = (const float*)d_in[3];
    const float* rec_b       = (const float*)d_in[4];
    const float* lig_g       = (const float*)d_in[5];
    const float* lig_b       = (const float*)d_in[6];
    const float* W_rec_qkv   = (const float*)d_in[7];
    const float* W_lig_qkv   = (const float*)d_in[8];
    const float* W_rr        = (const float*)d_in[9];
    const float* W_ll        = (const float*)d_in[10];
    const float* W_rl        = (const float*)d_in[11];
    const float* W_lr        = (const float*)d_in[12];
    const float* W_rec_fin   = (const float*)d_in[13];
    const float* b_rec_fin   = (const float*)d_in[14];
    const float* W_lig_fin   = (const float*)d_in[15];
    const float* b_lig_fin   = (const float*)d_in[16];

    float* ws      = (float*)d_ws;
    float* rqkv    = ws;                                   // 6 planes * 512 * 256
    float* lqkv    = rqkv + (size_t)NR * QKVD;             // 6 planes * 2048 * 256
    float* bias    = lqkv + (size_t)MM * NA * QKVD;        // 768*768*8
    float* rec_att = bias + (size_t)NN * NN * H;           // 512*256
    float* lig_att = rec_att + (size_t)NR * F;             // 2048*256

    // xn buffers ALIAS the att buffers (dead before attn runs; exact fit).
    float* xn_rec = rec_att;
    float* xn_lig = lig_att;

    ln_kernel<<<NR / 4, 256, 0, stream>>>(rec_profile, rec_g, rec_b, xn_rec, NR);
    ln_kernel<<<MM * NA / 4, 256, 0, stream>>>(lig_profile, lig_g, lig_b,
                                               xn_lig, MM * NA);
    qkv_gemm<<<dim3(NR / 4, 6), 256, 0, stream>>>(xn_rec, W_rec_qkv, rqkv, NR);
    qkv_gemm<<<dim3(MM * NA / 4, 6), 256, 0, stream>>>(xn_lig, W_lig_qkv,
                                                       lqkv, MM * NA);
    pair_bias_kernel<<<dim3(NN / 32, NN), 256, 0, stream>>>(pair, W_rr, W_ll,
                                                            W_rl, W_lr, bias);
    rr_add_kernel<<<NR, 256, 0, stream>>>(rqkv, bias);

    // rec_att must be zeroed AFTER qkv_gemm consumed xn_rec (same memory).
    hipMemsetAsync(rec_att, 0, (size_t)NR * F * sizeof(float), stream);

    attn_kernel<<<dim3(NN / 2, MM), 256, 0, stream>>>(rqkv, lqkv, bias,
                                                      rec_att, lig_att);

    float* rec_out = (float*)d_out;
    float* lig_out = rec_out + (size_t)NR * C1;
    final_gemm<<<NR / 4, 256, 0, stream>>>(rec_att, W_rec_fin, b_rec_fin,
                                           rec_out, NR);
    final_gemm<<<MM * NA / 4, 256, 0, stream>>>(lig_att, W_lig_fin, b_lig_fin,
                                                lig_out, MM * NA);
}

// Round 12
// 868.465 us; speedup vs baseline: 1.6738x; 1.0015x over previous
//
#include <hip/hip_runtime.h>
#include <hip/hip_bf16.h>

#define AC 32
#define H 8
#define C1 256
#define C2 128
#define NR 512
#define NA 256
#define MM 8
#define NN 768      // NR + NA
#define QKVD 1536   // AC * 6 * H
#define F 256       // AC * H planar feature dim

// Planar QKV layout: plane[role][row][c*8+h], role order = lq,lk,lv,rq,rk,rv
// (matches jnp.split chunk order within each 48-wide AC block).

// ---------------------------------------------------------------------------
// LayerNorm only: one 64-lane wave per row, 4 rows per block. No barriers.
// ---------------------------------------------------------------------------
__global__ __launch_bounds__(256) void ln_kernel(
    const float* __restrict__ in, const float* __restrict__ g,
    const float* __restrict__ b, float* __restrict__ xn, int nrows)
{
    const int t = threadIdx.x, w = t >> 6, lane = t & 63;
    const int row = blockIdx.x * 4 + w;
    if (row >= nrows) return;
    const float4 v = ((const float4*)(in + (size_t)row * C1))[lane];
    float s  = v.x + v.y + v.z + v.w;
    float s2 = v.x * v.x + v.y * v.y + v.z * v.z + v.w * v.w;
    #pragma unroll
    for (int off = 32; off; off >>= 1) {
        s  += __shfl_xor(s, off);
        s2 += __shfl_xor(s2, off);
    }
    const float mu = s * (1.0f / C1);
    const float rs = rsqrtf(s2 * (1.0f / C1) - mu * mu + 1e-5f);
    const float4 gv = ((const float4*)g)[lane];
    const float4 bv = ((const float4*)b)[lane];
    float4 o;
    o.x = (v.x - mu) * rs * gv.x + bv.x;
    o.y = (v.y - mu) * rs * gv.y + bv.y;
    o.z = (v.z - mu) * rs * gv.z + bv.z;
    o.w = (v.w - mu) * rs * gv.w + bv.w;
    ((float4*)(xn + (size_t)row * C1))[lane] = o;
}

// ---------------------------------------------------------------------------
// QKV projection GEMM, col-tiled: grid (nrows/4, 6). Block handles 4 rows ×
// 256 cols. Writes PLANAR output: out[(role*nrows + row)*256 + (c*8+h)].
// ---------------------------------------------------------------------------
__global__ __launch_bounds__(256) void qkv_gemm(
    const float* __restrict__ xn, const float* __restrict__ W,
    float* __restrict__ out, int nrows)
{
    __shared__ float x[4][C1];
    const int t = threadIdx.x;
    const int base = blockIdx.x * 4;
    #pragma unroll
    for (int r = 0; r < 4; ++r) x[r][t] = xn[(size_t)(base + r) * C1 + t];
    __syncthreads();

    const int col  = blockIdx.y * 256 + t;
    const int c    = col / 48;
    const int rem  = col - c * 48;
    const int role = rem >> 3;
    const int h    = rem & 7;
    const int f    = c * 8 + h;

    float a0 = 0.f, a1 = 0.f, a2 = 0.f, a3 = 0.f;
    #pragma unroll 4
    for (int cc = 0; cc < C1; ++cc) {
        const float w = W[(size_t)cc * QKVD + col];
        a0 += x[0][cc] * w;
        a1 += x[1][cc] * w;
        a2 += x[2][cc] * w;
        a3 += x[3][cc] * w;
    }
    float* op = out + ((size_t)role * nrows + base) * F + f;
    op[0 * F] = a0; op[1 * F] = a1; op[2 * F] = a2; op[3 * F] = a3;
}

// ---------------------------------------------------------------------------
// Pair-bias projection: bias[q][k][h] = factor * sum_c pair[q][k][c] * Wsel[c][h]
// One 32-lane group per (q,k); 8 groups/block; block loops 4 k-chunks
// (one q × 32 k's per block, W regs reused).
// Reduction = reduce-scatter butterfly: 9 shuffles/pair instead of 40.
// ---------------------------------------------------------------------------
__global__ __launch_bounds__(256) void pair_bias_kernel(
    const float* __restrict__ pair, const float* __restrict__ Wrr,
    const float* __restrict__ Wll, const float* __restrict__ Wrl,
    const float* __restrict__ Wlr, float* __restrict__ bias)
{
    const int t = threadIdx.x;
    const int grp = t >> 5, l = t & 31;
    const int q = blockIdx.y;
    const int kbase = blockIdx.x * 32;   // 32-chunks never straddle NR=512

    const float* W;
    if (q < NR) W = (kbase < NR) ? Wrr : Wrl;
    else        W = (kbase < NR) ? Wlr : Wll;

    const float factor = 0.17677669529663687f;  // 1/sqrt(32)

    float wreg[4][8];
    #pragma unroll
    for (int i = 0; i < 4; ++i) {
        const float4 a  = *(const float4*)(W + (size_t)(l * 4 + i) * H);
        const float4 b4 = *(const float4*)(W + (size_t)(l * 4 + i) * H + 4);
        wreg[i][0] = a.x * factor;  wreg[i][1] = a.y * factor;
        wreg[i][2] = a.z * factor;  wreg[i][3] = a.w * factor;
        wreg[i][4] = b4.x * factor; wreg[i][5] = b4.y * factor;
        wreg[i][6] = b4.z * factor; wreg[i][7] = b4.w * factor;
    }

    // lane's output h after reduce-scatter (bit-reversed 3-bit lane id)
    const int hsel = 4 * (l & 1) + 2 * ((l >> 1) & 1) + ((l >> 2) & 1);

    #pragma unroll
    for (int kk = 0; kk < 4; ++kk) {
        const int k = kbase + kk * 8 + grp;

        const float4 p = *(const float4*)(pair + ((size_t)q * NN + k) * C2 + l * 4);
        float pr[4] = {p.x, p.y, p.z, p.w};

        float acc[8];
        #pragma unroll
        for (int h = 0; h < 8; ++h)
            acc[h] = pr[0] * wreg[0][h] + pr[1] * wreg[1][h] +
                     pr[2] * wreg[2][h] + pr[3] * wreg[3][h];

        // ---- reduce-scatter over lane bits 0..2 (static indices only) ----
        // round 1 (xor 1): keep 4 of 8
        {
            const bool b = (l & 1) != 0;       // b=0 keep h0-3, b=1 keep h4-7
            float s0 = b ? acc[0] : acc[4];
            float s1 = b ? acc[1] : acc[5];
            float s2 = b ? acc[2] : acc[6];
            float s3 = b ? acc[3] : acc[7];
            const float r0 = __shfl_xor(s0, 1);
            const float r1 = __shfl_xor(s1, 1);
            const float r2 = __shfl_xor(s2, 1);
            const float r3 = __shfl_xor(s3, 1);
            acc[0] = (b ? acc[4] : acc[0]) + r0;
            acc[1] = (b ? acc[5] : acc[1]) + r1;
            acc[2] = (b ? acc[6] : acc[2]) + r2;
            acc[3] = (b ? acc[7] : acc[3]) + r3;
        }
        // round 2 (xor 2): keep 2 of 4
        {
            const bool b = (l & 2) != 0;
            float s0 = b ? acc[0] : acc[2];
            float s1 = b ? acc[1] : acc[3];
            const float r0 = __shfl_xor(s0, 2);
            const float r1 = __shfl_xor(s1, 2);
            acc[0] = (b ? acc[2] : acc[0]) + r0;
            acc[1] = (b ? acc[3] : acc[1]) + r1;
        }
        // round 3 (xor 4): keep 1 of 2
        float v;
        {
            const bool b = (l & 4) != 0;
            float s0 = b ? acc[0] : acc[1];
            const float r0 = __shfl_xor(s0, 4);
            v = (b ? acc[1] : acc[0]) + r0;
        }
        // full-sum butterflies across remaining lane bits (same h at l^8, l^16)
        v += __shfl_xor(v, 8);
        v += __shfl_xor(v, 16);

        if (l < 8)
            bias[((size_t)q * NN + k) * H + hsel] = v;
    }
}

// ---------------------------------------------------------------------------
// rr fold: bias[q][k][h] += rec_rq[q]·rec_rk[k] (per head), q,k < NR.
// m-independent — computed once instead of in all 8 m-replicas.
// ---------------------------------------------------------------------------
__global__ __launch_bounds__(256) void rr_add_kernel(
    const float* __restrict__ rqkv, float* __restrict__ bias)
{
    __shared__ __align__(16) float qv[F];
    const int t = threadIdx.x;
    const int q = blockIdx.x;
    const size_t RSTR = (size_t)NR * F;
    qv[t] = rqkv[3 * RSTR + (size_t)q * F + t];   // rec_rq plane
    __syncthreads();
    const float4* q4 = (const float4*)qv;
    const float* recK = rqkv + 4 * RSTR;          // rec_rk plane

    #pragma unroll
    for (int rep = 0; rep < 2; ++rep) {
        const int k = rep * 256 + t;
        const float4* krow = (const float4*)(recK + (size_t)k * F);
        float acc[8] = {0.f, 0.f, 0.f, 0.f, 0.f, 0.f, 0.f, 0.f};
        #pragma unroll 8
        for (int j = 0; j < 64; ++j) {
            const float4 kv = krow[j];
            const float4 qq = q4[j];
            const int hb = (j & 1) * 4;
            acc[hb + 0] += qq.x * kv.x;
            acc[hb + 1] += qq.y * kv.y;
            acc[hb + 2] += qq.z * kv.z;
            acc[hb + 3] += qq.w * kv.w;
        }
        float* bp = bias + ((size_t)q * NN + k) * H;
        const float4 b1 = ((const float4*)bp)[0];
        const float4 b2 = ((const float4*)bp)[1];
        ((float4*)bp)[0] = make_float4(acc[0] + b1.x, acc[1] + b1.y,
                                       acc[2] + b1.z, acc[3] + b1.w);
        ((float4*)bp)[1] = make_float4(acc[4] + b2.x, acc[5] + b2.y,
                                       acc[6] + b2.z, acc[7] + b2.w);
    }
}

// ---------------------------------------------------------------------------
// Flash-tiled fused attention, TQ=2 q-rows per block, 3 k-tiles of 256 with
// online softmax. LDS ~25 KB. One block per (m, q-pair).
// PV is group-split: wave g handles keys [g*64,g*64+64) of the tile, each
// lane owns 4 features and loads V as float4 (coalesced 1KB/wave/instr).
// Cross-group partials reduced via redf (aliases ptile, dead after last tile).
// Top rows read the rr quadrant of `bias` as ready logits (rr_add folded).
// ---------------------------------------------------------------------------
__global__ __launch_bounds__(256) void attn_kernel(
    const float* __restrict__ rqkv, const float* __restrict__ lqkv,
    const float* __restrict__ bias, float* __restrict__ rec_att,
    float* __restrict__ lig_att)
{
    __shared__ __align__(16) float qA[2][F];   // rq role (vs rec keys)
    __shared__ __align__(16) float qB[2][F];   // lq role (vs lig keys)
    __shared__ __align__(16) float ptile[2][256][9];  // stride 9: conflict-free
    __shared__ float red2[2][32][8];
    __shared__ __align__(16) float Mrun[2][8], Drun[2][8], fct[2][8];

    const int t = threadIdx.x;
    const int q0 = blockIdx.x * 2, m = blockIdx.y;
    const bool top = q0 < NR;                  // NR even → pair same side

    const size_t RSTR = (size_t)NR * F;
    const size_t LSTR = (size_t)MM * NA * F;
    const float* recP = rqkv;
    const float* ligP = lqkv + (size_t)m * NA * F;

    #pragma unroll
    for (int r = 0; r < 2; ++r) {
        const float* qrow = top ? (recP + (size_t)(q0 + r) * F)
                                : (ligP + (size_t)(q0 + r - NR) * F);
        const size_t str = top ? RSTR : LSTR;
        qA[r][t] = qrow[3 * str + t];
        qB[r][t] = qrow[0 * str + t];
    }
    if (t < 16) { Mrun[t >> 3][t & 7] = -1e30f; Drun[t >> 3][t & 7] = 0.f; }
    __syncthreads();

    const float* recK = recP + (top ? 4 : 1) * RSTR;
    const float* ligK = ligP + (top ? 4 : 1) * LSTR;
    const float* Vrec = recP + (top ? 5 : 2) * RSTR;
    const float* Vlig = ligP + (top ? 5 : 2) * LSTR;

    const int h = t & 7, s = t >> 3;
    const int g_pv = t >> 6;            // wave id = PV key-group
    const int u_pv = t & 63;            // lane: owns features 4u..4u+3
    const int hb4 = 4 * (t & 1);        // head-quad of those features

    float aR[2][4] = {{0.f, 0.f, 0.f, 0.f}, {0.f, 0.f, 0.f, 0.f}};
    float aL[2][4] = {{0.f, 0.f, 0.f, 0.f}, {0.f, 0.f, 0.f, 0.f}};

    for (int tl = 0; tl < 3; ++tl) {
        const int kbase = tl * 256;
        // ---- logits tile ----
        if (top && tl < 2) {
            #pragma unroll
            for (int r = 0; r < 2; ++r) {
                const float* bp = bias + ((size_t)(q0 + r) * NN + kbase + t) * H;
                const float4 b1 = ((const float4*)bp)[0];
                const float4 b2 = ((const float4*)bp)[1];
                ptile[r][t][0] = b1.x; ptile[r][t][1] = b1.y;
                ptile[r][t][2] = b1.z; ptile[r][t][3] = b1.w;
                ptile[r][t][4] = b2.x; ptile[r][t][5] = b2.y;
                ptile[r][t][6] = b2.z; ptile[r][t][7] = b2.w;
            }
        } else {
            const float4* krow = (const float4*)((tl < 2)
                ? (recK + (size_t)(kbase + t) * F)
                : (ligK + (size_t)t * F));
            float acc[2][8] = {{0.f}};
            #pragma unroll 8
            for (int j = 0; j < 64; ++j) {
                const float4 kv = krow[j];
                const int hb = (j & 1) * 4;
                #pragma unroll
                for (int r = 0; r < 2; ++r) {
                    const float4 qq = (tl < 2) ? ((const float4*)qA[r])[j]
                                               : ((const float4*)qB[r])[j];
                    acc[r][hb + 0] += qq.x * kv.x;
                    acc[r][hb + 1] += qq.y * kv.y;
                    acc[r][hb + 2] += qq.z * kv.z;
                    acc[r][hb + 3] += qq.w * kv.w;
                }
            }
            #pragma unroll
            for (int r = 0; r < 2; ++r) {
                const float* bp = bias + ((size_t)(q0 + r) * NN + kbase + t) * H;
                const float4 b1 = ((const float4*)bp)[0];
                const float4 b2 = ((const float4*)bp)[1];
                ptile[r][t][0] = acc[r][0] + b1.x; ptile[r][t][1] = acc[r][1] + b1.y;
                ptile[r][t][2] = acc[r][2] + b1.z; ptile[r][t][3] = acc[r][3] + b1.w;
                ptile[r][t][4] = acc[r][4] + b2.x; ptile[r][t][5] = acc[r][5] + b2.y;
                ptile[r][t][6] = acc[r][6] + b2.z; ptile[r][t][7] = acc[r][7] + b2.w;
            }
        }
        __syncthreads();

        // ---- tile max per (r,h) ----
        #pragma unroll
        for (int r = 0; r < 2; ++r) {
            float pm = ptile[r][s * 8][h];
            #pragma unroll
            for (int j = 1; j < 8; ++j) pm = fmaxf(pm, ptile[r][s * 8 + j][h]);
            red2[r][s][h] = pm;
        }
        __syncthreads();
        if (t < 16) {
            const int r = t >> 3, hh = t & 7;
            float mx = red2[r][0][hh];
            for (int s2 = 1; s2 < 32; ++s2) mx = fmaxf(mx, red2[r][s2][hh]);
            const float Mo = Mrun[r][hh];
            const float Mn = fmaxf(Mo, mx);
            fct[r][hh]  = __expf(Mo - Mn);
            Mrun[r][hh] = Mn;
        }
        __syncthreads();

        // ---- exp + partial sums; rescale accumulators (per-feature fct) ----
        #pragma unroll
        for (int r = 0; r < 2; ++r) {
            const float Mn = Mrun[r][h];
            float ps = 0.f;
            #pragma unroll
            for (int j = 0; j < 8; ++j) {
                const int kk = s * 8 + j;
                const float e = __expf(ptile[r][kk][h] - Mn);
                ptile[r][kk][h] = e;
                ps += e;
            }
            red2[r][s][h] = ps;
        }
        {
            const float4 f0 = *(const float4*)&fct[0][hb4];
            const float4 f1 = *(const float4*)&fct[1][hb4];
            aR[0][0] *= f0.x; aR[0][1] *= f0.y; aR[0][2] *= f0.z; aR[0][3] *= f0.w;
            aL[0][0] *= f0.x; aL[0][1] *= f0.y; aL[0][2] *= f0.z; aL[0][3] *= f0.w;
            aR[1][0] *= f1.x; aR[1][1] *= f1.y; aR[1][2] *= f1.z; aR[1][3] *= f1.w;
            aL[1][0] *= f1.x; aL[1][1] *= f1.y; aL[1][2] *= f1.z; aL[1][3] *= f1.w;
        }
        __syncthreads();
        if (t < 16) {
            const int r = t >> 3, hh = t & 7;
            float ts = 0.f;
            for (int s2 = 0; s2 < 32; ++s2) ts += red2[r][s2][hh];
            Drun[r][hh] = Drun[r][hh] * fct[r][hh] + ts;
        }

        // ---- PV over this tile: group-split, float4 V loads ----
        const bool doPV = (tl == 2) || (!top) || (m == 0);
        if (doPV) {
            if (tl < 2) {
                const float* Vp = Vrec + (size_t)kbase * F;
                #pragma unroll 8
                for (int kk2 = 0; kk2 < 64; ++kk2) {
                    const int kk = g_pv * 64 + kk2;
                    const float4 v4 = *(const float4*)(Vp + (size_t)kk * F + 4 * u_pv);
                    #pragma unroll
                    for (int r = 0; r < 2; ++r) {
                        aR[r][0] += ptile[r][kk][hb4 + 0] * v4.x;
                        aR[r][1] += ptile[r][kk][hb4 + 1] * v4.y;
                        aR[r][2] += ptile[r][kk][hb4 + 2] * v4.z;
                        aR[r][3] += ptile[r][kk][hb4 + 3] * v4.w;
                    }
                }
            } else {
                #pragma unroll 8
                for (int kk2 = 0; kk2 < 64; ++kk2) {
                    const int kk = g_pv * 64 + kk2;
                    const float4 v4 = *(const float4*)(Vlig + (size_t)kk * F + 4 * u_pv);
                    #pragma unroll
                    for (int r = 0; r < 2; ++r) {
                        aL[r][0] += ptile[r][kk][hb4 + 0] * v4.x;
                        aL[r][1] += ptile[r][kk][hb4 + 1] * v4.y;
                        aL[r][2] += ptile[r][kk][hb4 + 2] * v4.z;
                        aL[r][3] += ptile[r][kk][hb4 + 3] * v4.w;
                    }
                }
            }
        }
        __syncthreads();
    }

    // ---- cross-group reduction (redf aliases ptile; ptile dead now) ----
    float* redf = &ptile[0][0][0];      // [4 groups][2 rows][2 RL][256 feats]
    #pragma unroll
    for (int r = 0; r < 2; ++r) {
        *(float4*)(redf + ((g_pv * 2 + r) * 2 + 0) * 256 + 4 * u_pv) =
            make_float4(aR[r][0], aR[r][1], aR[r][2], aR[r][3]);
        *(float4*)(redf + ((g_pv * 2 + r) * 2 + 1) * 256 + 4 * u_pv) =
            make_float4(aL[r][0], aL[r][1], aL[r][2], aL[r][3]);
    }
    __syncthreads();
    float R0 = 0.f, L0 = 0.f, R1 = 0.f, L1 = 0.f;
    #pragma unroll
    for (int g2 = 0; g2 < 4; ++g2) {
        R0 += redf[((g2 * 2 + 0) * 2 + 0) * 256 + t];
        L0 += redf[((g2 * 2 + 0) * 2 + 1) * 256 + t];
        R1 += redf[((g2 * 2 + 1) * 2 + 0) * 256 + t];
        L1 += redf[((g2 * 2 + 1) * 2 + 1) * 256 + t];
    }

    const float i0 = 1.0f / Drun[0][h];
    const float i1 = 1.0f / Drun[1][h];
    if (top) {
        atomicAdd(&rec_att[(size_t)q0 * F + t],       i0 * (R0 + 0.125f * L0));
        atomicAdd(&rec_att[(size_t)(q0 + 1) * F + t], i1 * (R1 + 0.125f * L1));
    } else {
        const int i = q0 - NR;
        lig_att[((size_t)m * NA + i) * F + t]     = i0 * (R0 + L0);
        lig_att[((size_t)m * NA + i + 1) * F + t] = i1 * (R1 + L1);
    }
}

// ---------------------------------------------------------------------------
// Final projection: out[row][d] = att[row][:] @ W[:, d] + b[d]. 4 rows/block.
// ---------------------------------------------------------------------------
__global__ __launch_bounds__(256) void final_gemm(
    const float* __restrict__ att, const float* __restrict__ W,
    const float* __restrict__ bfin, float* __restrict__ out, int nrows)
{
    __shared__ float x[4][C1];
    const int t = threadIdx.x;
    const int base = blockIdx.x * 4;
    #pragma unroll
    for (int r = 0; r < 4; ++r) x[r][t] = att[(size_t)(base + r) * C1 + t];
    __syncthreads();
    float a0 = 0.f, a1 = 0.f, a2 = 0.f, a3 = 0.f;
    #pragma unroll 4
    for (int cc = 0; cc < C1; ++cc) {
        const float w = W[(size_t)cc * C1 + t];
        a0 += x[0][cc] * w;
        a1 += x[1][cc] * w;
        a2 += x[2][cc] * w;
        a3 += x[3][cc] * w;
    }
    const float bb = bfin[t];
    out[(size_t)(base + 0) * C1 + t] = a0 + bb;
    out[(size_t)(base + 1) * C1 + t] = a1 + bb;
    out[(size_t)(base + 2) * C1 + t] = a2 + bb;
    out[(size_t)(base + 3) * C1 + t] = a3 + bb;
}

// ---------------------------------------------------------------------------
extern "C" void kernel_launch(void* const* d_in, const int* in_sizes, int n_in,
                              void* d_out, int out_size, void* d_ws, size_t ws_size,
                              hipStream_t stream) {
    const float* rec_profile = (const float*)d_in[0];
    const float* lig_profile = (const float*)d_in[1];
    const float* pair        = (const float*)d_in[2];
    const float* rec_g       = (const float*)d_in[3];
    const float* rec_b       = (const float*)d_in[4];
    const float* lig_g       = (const float*)d_in[5];
    const float* lig_b       = (const float*)d_in[6];
    const float* W_rec_qkv   = (const float*)d_in[7];
    const float* W_lig_qkv   = (const float*)d_in[8];
    const float* W_rr        = (const float*)d_in[9];
    const float* W_ll        = (const float*)d_in[10];
    const float* W_rl        = (const float*)d_in[11];
    const float* W_lr        = (const float*)d_in[12];
    const float* W_rec_fin   = (const float*)d_in[13];
    const float* b_rec_fin   = (const float*)d_in[14];
    const float* W_lig_fin   = (const float*)d_in[15];
    const float* b_lig_fin   = (const float*)d_in[16];

    float* ws      = (float*)d_ws;
    float* rqkv    = ws;                                   // 6 planes * 512 * 256
    float* lqkv    = rqkv + (size_t)NR * QKVD;             // 6 planes * 2048 * 256
    float* bias    = lqkv + (size_t)MM * NA * QKVD;        // 768*768*8
    float* rec_att = bias + (size_t)NN * NN * H;           // 512*256
    float* lig_att = rec_att + (size_t)NR * F;             // 2048*256

    // xn buffers ALIAS the att buffers (dead before attn runs; exact fit).
    float* xn_rec = rec_att;
    float* xn_lig = lig_att;

    ln_kernel<<<NR / 4, 256, 0, stream>>>(rec_profile, rec_g, rec_b, xn_rec, NR);
    ln_kernel<<<MM * NA / 4, 256, 0, stream>>>(lig_profile, lig_g, lig_b,
                                               xn_lig, MM * NA);
    qkv_gemm<<<dim3(NR / 4, 6), 256, 0, stream>>>(xn_rec, W_rec_qkv, rqkv, NR);
    qkv_gemm<<<dim3(MM * NA / 4, 6), 256, 0, stream>>>(xn_lig, W_lig_qkv,
                                                       lqkv, MM * NA);
    pair_bias_kernel<<<dim3(NN / 32, NN), 256, 0, stream>>>(pair, W_rr, W_ll,
                                                            W_rl, W_lr, bias);
    rr_add_kernel<<<NR, 256, 0, stream>>>(rqkv, bias);

    // rec_att must be zeroed AFTER qkv_gemm consumed xn_rec (same memory).
    hipMemsetAsync(rec_att, 0, (size_t)NR * F * sizeof(float), stream);

    attn_kernel<<<dim3(NN / 2, MM), 256, 0, stream>>>(rqkv, lqkv, bias,
                                                      rec_att, lig_att);

    float* rec_out = (float*)d_out;
    float* lig_out = rec_out + (size_t)NR * C1;
    final_gemm<<<NR / 4, 256, 0, stream>>>(rec_att, W_rec_fin, b_rec_fin,
                                           rec_out, NR);
    final_gemm<<<MM * NA / 4, 256, 0, stream>>>(lig_att, W_lig_fin, b_lig_fin,
                                                lig_out, MM * NA);
}